// Round 9
// baseline (164.921 us; speedup 1.0000x reference)
//
#include <hip/hip_runtime.h>
#include <math.h>

#define S_LEN 1024
#define NHEAD 8
#define BATCH 8
#define KDIM  64
#define HID   32
#define NT    2048
#define LOG2E 1.4426950408889634f
#define TRI(q) ((q) * ((q) + 1) / 2)
// key-order bit-shuffle: m=[nb1 nb0 q1 q0 r1 r0] -> key=[nb1 q1 q0 nb0 r1 r0]
#define PERM(m) (((m) & 0x20) | (((m) & 0x0C) << 1) | (((m) & 0x10) >> 2) | ((m) & 3))
// LDS column swizzle key per row (3 bits, conflict-free for K(perm) and V reads)
#define SWZ(row) (((((row) >> 3) & 1) << 2) | ((row) & 3))

typedef __attribute__((ext_vector_type(8))) short bf16x8;
typedef __attribute__((ext_vector_type(4))) float f32x4;
typedef unsigned short ushort_t;

__device__ inline ushort_t f2bf(float f) {
  union { float f; unsigned u; } v; v.f = f;
  unsigned u = v.u;
  return (ushort_t)((u + 0x7FFFu + ((u >> 16) & 1u)) >> 16);
}
__device__ inline float bf2f(ushort_t u) {
  union { unsigned x; float f; } v; v.x = ((unsigned)u) << 16; return v.f;
}
__device__ inline unsigned cvtpk_bf16(float lo, float hi) {
  unsigned r;
  asm("v_cvt_pk_bf16_f32 %0, %1, %2" : "=v"(r) : "v"(lo), "v"(hi));
  return r;
}

// async global->LDS 16B: lane's LDS dest = lds_base + lane*16 (wave-uniform base)
__device__ inline void gl_lds16(const ushort_t* g, ushort_t* l) {
  __builtin_amdgcn_global_load_lds(
      (const __attribute__((address_space(1))) unsigned int*)g,
      (__attribute__((address_space(3))) unsigned int*)l, 16, 0, 0);
}

// ---------------------------------------------------------------------------
// Kernel 1: prep = to_bf16 (blocks 0..5119) + fire_tables (blocks 5120..7175).
// At its ~38 MB memory floor (~6-7 us). Q weights pre-scaled by
// (1/sqrt(KD))*log2e and the FIRE bias table by log2e (softmax = bare exp2).
// ---------------------------------------------------------------------------
__global__ __launch_bounds__(256) void prep(
    const float* __restrict__ s, const float* __restrict__ wq,
    const float* __restrict__ wk, const float* __restrict__ wv,
    const float* __restrict__ wo,
    ushort_t* __restrict__ sb, ushort_t* __restrict__ wqb,
    ushort_t* __restrict__ wkb, ushort_t* __restrict__ wvb,
    ushort_t* __restrict__ wob,
    const float* __restrict__ c_raw, const float* __restrict__ Lp,
    const float* __restrict__ w1, const float* __restrict__ b1,
    const float* __restrict__ W2, const float* __restrict__ b2,
    const float* __restrict__ w3, const float* __restrict__ b3,
    float* __restrict__ num_g, float* __restrict__ rden_g,
    float* __restrict__ gtab_g) {
  __shared__ float h1s[8][33];
  const int bx = blockIdx.x;
  const int tid = threadIdx.x;
  if (bx < 5120) {
    const float* src; ushort_t* dst; int base; float scale = 1.0f;
    if (bx < 4096)      { src = s;  dst = sb;  base = bx; }
    else if (bx < 4352) { src = wq; dst = wqb; base = bx - 4096; scale = 0.125f * LOG2E; }
    else if (bx < 4608) { src = wk; dst = wkb; base = bx - 4352; }
    else if (bx < 4864) { src = wv; dst = wvb; base = bx - 4608; }
    else                { src = wo; dst = wob; base = bx - 4864; }
    const int i = (base * 256 + tid) * 4;
    float4 v = *(const float4*)&src[i];
    ushort4 o;
    o.x = f2bf(v.x * scale); o.y = f2bf(v.y * scale);
    o.z = f2bf(v.z * scale); o.w = f2bf(v.w * scale);
    *(ushort4*)&dst[i] = o;
  } else {
    const int idx = bx - 5120;
    const int h = idx / 257;
    const int xb = idx % 257;
    const float cr = c_raw[h];
    const float c = (cr > 20.f) ? cr : log1pf(expf(cr));
    const int gid = xb * 256 + tid;
    if (gid < S_LEN) {
      num_g[h * S_LEN + gid] = log1pf(c * (float)gid);
      rden_g[h * S_LEN + gid] = 1.0f / log1pf(c * fmaxf(Lp[h], (float)(gid + 1)));
    }
    const int pl = tid >> 5;             // point-local 0..7
    const int j = tid & 31;              // hidden dim
    const int pt = xb * 8 + pl;
    const float x = (float)pt * (1.0f / NT);
    float v = x * w1[h * HID + j] + b1[h * HID + j];
    h1s[pl][j] = 0.5f * v * (1.0f + erff(v * 0.70710678118f));
    __syncthreads();
    float sm = b2[h * HID + j];
    const float* w2r = W2 + ((size_t)(h * HID + j)) * HID;
    #pragma unroll
    for (int k = 0; k < HID; ++k) sm += w2r[k] * h1s[pl][k];
    float g = 0.5f * sm * (1.0f + erff(sm * 0.70710678118f));
    float y = w3[h * HID + j] * g;
    #pragma unroll
    for (int off = 1; off < 32; off <<= 1) y += __shfl_xor(y, off);
    if (j == 0 && pt <= NT) gtab_g[h * (NT + 1) + pt] = (y + b3[h]) * LOG2E;
  }
}

// ---------------------------------------------------------------------------
// Z-FUSED QKV tile, BM=128 (R9): one block computes Q, K, V for a 128x64
// (m0,n0) tile from a SINGLE A staging. LDS 40 KB = A(16K) + Wq/Wk/Wv(24K),
// acc[3][2][4] (96 VGPR), 48 MFMA per barrier-pair (R8: 24). Extends the
// R8-measured lever: compute density per barrier-drain doubled again, and
// serial 8-step barrier chains per CU halved (512 QKV blocks vs 1024).
// ---------------------------------------------------------------------------
__device__ __forceinline__ void qkv_tile(
    ushort_t* sAB, const ushort_t* __restrict__ A,
    const ushort_t* __restrict__ Wq_, const ushort_t* __restrict__ Wk_,
    const ushort_t* __restrict__ Wv_,
    ushort_t* __restrict__ Qo, ushort_t* __restrict__ Ko,
    ushort_t* __restrict__ Vto, int m0, int n0, int tid) {
  ushort_t* sA = sAB;                  // 128x64 bf16 = 16 KB
  ushort_t* sW = sAB + 8192;           // 3 x 8 KB, z-major
  const int lane = tid & 63, w = tid >> 6, quad = lane >> 4, l16 = lane & 15;
  f32x4 acc[3][2][4];
  #pragma unroll
  for (int z = 0; z < 3; ++z)
    #pragma unroll
    for (int mi = 0; mi < 2; ++mi)
      #pragma unroll
      for (int nb = 0; nb < 4; ++nb) acc[z][mi][nb] = (f32x4)0.0f;

  const int r8 = lane >> 3;          // row within 8-row staging group
  const int gc = (lane & 7) ^ r8;    // swizzled source chunk for this lane
  const int sw = l16 & 7;            // frag-read swizzle key
  const ushort_t* Wz[3] = {Wq_, Wk_, Wv_};

  for (int kt = 0; kt < 512; kt += 64) {
    __syncthreads();
    #pragma unroll
    for (int j = 0; j < 4; ++j) {
      const int row = w * 32 + j * 8 + r8;
      gl_lds16(&A[(size_t)(m0 + row) * 512 + kt + gc * 8], &sA[(w * 32 + j * 8) * 64]);
    }
    #pragma unroll
    for (int z = 0; z < 3; ++z)
      #pragma unroll
      for (int j = 0; j < 2; ++j) {
        const int row = w * 16 + j * 8 + r8;
        gl_lds16(&Wz[z][(size_t)(n0 + row) * 512 + kt + gc * 8],
                 &sW[z * 4096 + (w * 16 + j * 8) * 64]);
      }
    __syncthreads();
    #pragma unroll
    for (int ks = 0; ks < 2; ++ks) {
      const int off = ((ks * 4 + quad) ^ sw) * 8;
      bf16x8 af[2];
      #pragma unroll
      for (int mi = 0; mi < 2; ++mi)
        af[mi] = *(const bf16x8*)&sA[(w * 32 + mi * 16 + l16) * 64 + off];
      #pragma unroll
      for (int z = 0; z < 3; ++z)
        #pragma unroll
        for (int nb = 0; nb < 4; ++nb) {
          bf16x8 wf = *(const bf16x8*)&sW[z * 4096 + (nb * 16 + l16) * 64 + off];
          #pragma unroll
          for (int mi = 0; mi < 2; ++mi)
            acc[z][mi][nb] = __builtin_amdgcn_mfma_f32_16x16x32_bf16(af[mi], wf, acc[z][mi][nb], 0, 0, 0);
        }
    }
  }

  // ---- epilogue. z=0 (Q), z=1 (K): bf16 scatter [b,h,s,kd] (no LDS).
  const int bb = m0 >> 10, sbase = m0 & 1023;
  #pragma unroll
  for (int z = 0; z < 2; ++z) {
    ushort_t* outp = z ? Ko : Qo;
    #pragma unroll
    for (int mi = 0; mi < 2; ++mi)
      #pragma unroll
      for (int nb = 0; nb < 4; ++nb)
        #pragma unroll
        for (int r = 0; r < 4; ++r) {
          int m = m0 + w * 32 + mi * 16 + quad * 4 + r;
          int n = n0 + nb * 16 + l16;
          int ss = m & 1023, hh = n >> 6, kd = n & 63;
          outp[(((size_t)(bb * NHEAD + hh)) * S_LEN + ss) * KDIM + kd] = f2bf(acc[z][mi][nb][r]);
        }
  }
  // z=2 (V): V^T via LDS transpose (XOR-swizzled [n=64][m=128] = 16 KB)
  __syncthreads();
  #pragma unroll
  for (int mi = 0; mi < 2; ++mi)
    #pragma unroll
    for (int nb = 0; nb < 4; ++nb)
      #pragma unroll
      for (int r = 0; r < 4; ++r) {
        int nl = nb * 16 + l16;
        int ml = w * 32 + mi * 16 + quad * 4 + r;
        sAB[nl * 128 + (((ml >> 3) ^ (nl & 7)) * 8) + (ml & 7)] = f2bf(acc[2][mi][nb][r]);
      }
  __syncthreads();
  const int nl = tid >> 2, seg = tid & 3;
  const int ng = n0 + nl, hh = ng >> 6, kd = ng & 63;
  ushort_t* vout = Vto + (((size_t)(bb * NHEAD + hh)) * KDIM + kd) * S_LEN;
  #pragma unroll
  for (int c2 = 0; c2 < 4; ++c2) {
    int mc = seg * 4 + c2;               // 0..15 (16 chunks of 8 over m=128)
    bf16x8 vr = *(bf16x8*)&sAB[nl * 128 + ((mc ^ (nl & 7)) * 8)];
    *(bf16x8*)&vout[sbase + mc * 8] = vr;
  }
}

// ---------------------------------------------------------------------------
// Plain GEMM tile (out-proj), BM=128: C = A(Mx512 bf16) * W^T, 128x64 tile,
// LDS 24 KB = A(16K)+W(8K), acc[2][4], 16 MFMA per barrier-pair. f32 out.
// ---------------------------------------------------------------------------
__device__ __forceinline__ void gemm_tile(
    ushort_t* sAB, const ushort_t* __restrict__ A, const ushort_t* __restrict__ Wp,
    float* __restrict__ outp, int m0, int n0, int tid) {
  ushort_t* sA = sAB;            // 128x64 = 16 KB
  ushort_t* sB = sAB + 8192;     // 64x64 = 8 KB
  const int lane = tid & 63, w = tid >> 6, quad = lane >> 4, l16 = lane & 15;
  f32x4 acc[2][4];
  #pragma unroll
  for (int mi = 0; mi < 2; ++mi)
    #pragma unroll
    for (int nb = 0; nb < 4; ++nb) acc[mi][nb] = (f32x4)0.0f;

  const int r8 = lane >> 3;
  const int gc = (lane & 7) ^ r8;
  const int sw = l16 & 7;

  for (int kt = 0; kt < 512; kt += 64) {
    __syncthreads();
    #pragma unroll
    for (int j = 0; j < 4; ++j) {
      const int row = w * 32 + j * 8 + r8;
      gl_lds16(&A[(size_t)(m0 + row) * 512 + kt + gc * 8], &sA[(w * 32 + j * 8) * 64]);
    }
    #pragma unroll
    for (int j = 0; j < 2; ++j) {
      const int row = w * 16 + j * 8 + r8;
      gl_lds16(&Wp[(size_t)(n0 + row) * 512 + kt + gc * 8], &sB[(w * 16 + j * 8) * 64]);
    }
    __syncthreads();
    #pragma unroll
    for (int ks = 0; ks < 2; ++ks) {
      const int off = ((ks * 4 + quad) ^ sw) * 8;
      bf16x8 af[2];
      #pragma unroll
      for (int mi = 0; mi < 2; ++mi)
        af[mi] = *(const bf16x8*)&sA[(w * 32 + mi * 16 + l16) * 64 + off];
      #pragma unroll
      for (int nb = 0; nb < 4; ++nb) {
        bf16x8 bfr = *(const bf16x8*)&sB[(nb * 16 + l16) * 64 + off];
        #pragma unroll
        for (int mi = 0; mi < 2; ++mi)
          acc[mi][nb] = __builtin_amdgcn_mfma_f32_16x16x32_bf16(af[mi], bfr, acc[mi][nb], 0, 0, 0);
      }
    }
  }
  #pragma unroll
  for (int mi = 0; mi < 2; ++mi)
    #pragma unroll
    for (int nb = 0; nb < 4; ++nb)
      #pragma unroll
      for (int r = 0; r < 4; ++r) {
        int m = m0 + w * 32 + mi * 16 + quad * 4 + r;
        int n = n0 + nb * 16 + l16;
        outp[(size_t)m * 512 + n] = acc[mi][nb][r];
      }
}

// ---------------------------------------------------------------------------
// Kernel 2/4: gemm_bias. scatter=1: blocks < nGemm are z-fused 128x64 QKV
// tiles (512 blocks, m0=(tile&63)*128, n0=(tile>>6)*64); blocks >= nGemm
// are bias-pre. scatter=0: out-proj 128x64 (512 blocks, f32 out).
// ---------------------------------------------------------------------------
__global__ __launch_bounds__(256) void gemm_bias(
    const ushort_t* __restrict__ A,
    const ushort_t* __restrict__ W0, const ushort_t* __restrict__ W1,
    const ushort_t* __restrict__ W2w,
    void* __restrict__ out0, void* __restrict__ out1, void* __restrict__ out2,
    int scatter, int nGemm,
    const float* __restrict__ num_g, const float* __restrict__ rden_g,
    const float* __restrict__ gtab_g, ushort_t* __restrict__ biaspre) {
  __shared__ __align__(16) ushort_t sAB[20480];   // 40 KB
  const int tid = threadIdx.x;
  if ((int)blockIdx.x < nGemm) {
    const int tile = blockIdx.x;
    const int m0 = (tile & 63) * 128;
    const int n0 = (tile >> 6) * 64;
    if (scatter) {
      qkv_tile(sAB, A, W0, W1, W2w, (ushort_t*)out0, (ushort_t*)out1,
               (ushort_t*)out2, m0, n0, tid);
    } else {
      gemm_tile(sAB, A, W0, (float*)out0, m0, n0, tid);
    }
  } else {
    const int idx = blockIdx.x - nGemm;      // 0..543
    const int h = idx / 68;
    const int pair = idx % 68;
    float* gtab_s = (float*)sAB;             // 2049 floats
    float* num_s = gtab_s + 2052;            // 1024 floats
    float* rden_s = num_s + 1024;            // [2][64]  (total ~12.9 KB < 40 KB)
    for (int i = tid; i <= NT; i += 256) gtab_s[i] = gtab_g[h * (NT + 1) + i];
    for (int i = tid; i < S_LEN; i += 256) num_s[i] = num_g[h * S_LEN + i];
    const int sub = tid >> 7, tid2 = tid & 127;
    const int tileIdx = pair * 2 + sub;
    int qt = 0;
    while (TRI(qt + 1) <= tileIdx) ++qt;
    const int t = tileIdx - TRI(qt);
    if (tid2 < 64) rden_s[sub * 64 + tid2] = rden_g[h * S_LEN + qt * 64 + tid2];
    __syncthreads();
    const int w = tid2 >> 6, lane = tid2 & 63, quad = lane >> 4, l16 = lane & 15;
    ushort_t vals[32];
    #pragma unroll
    for (int qg = 0; qg < 2; ++qg) {
      const int iloc = w * 32 + qg * 16 + l16;
      const int i = qt * 64 + iloc;
      const float rden = rden_s[sub * 64 + iloc];
      #pragma unroll
      for (int nb = 0; nb < 4; ++nb)
        #pragma unroll
        for (int r = 0; r < 4; ++r) {
          const int m = nb * 16 + quad * 4 + r;
          const int j = t * 64 + PERM(m);
          ushort_t out;
          if (j > i) {
            out = 0xFF80;  // bf16 -inf (causal)
          } else {
            const int d = i - j;
            float x = num_s[d] * rden;       // in [0,1)
            float tf = x * (float)NT;
            int it = (int)tf; it = it < (NT - 1) ? it : (NT - 1);
            float fr = tf - (float)it;
            float ga = gtab_s[it];
            out = f2bf(ga + (gtab_s[it + 1] - ga) * fr);
          }
          vals[qg * 16 + nb * 4 + r] = out;
        }
    }
    ushort_t* dst = &biaspre[((size_t)(h * 136 + tileIdx) * 128 + tid2) * 32];
    uint4 u[2];
    #pragma unroll
    for (int half = 0; half < 2; ++half) {
      #pragma unroll
      for (int v = 0; v < 8; ++v) ((ushort_t*)&u[0])[v] = vals[half * 16 + v];
      #pragma unroll
      for (int v = 0; v < 8; ++v) ((ushort_t*)&u[1])[v] = vals[half * 16 + 8 + v];
      *(uint4*)(dst + half * 16) = u[0];
      *(uint4*)(dst + half * 16 + 8) = u[1];
    }
  }
}

// ---------------------------------------------------------------------------
// Kernel 3: transposed MFMA causal flash attention, SPLIT-KV (R7 config,
// measured -7 us). 1024 blocks x 256 thr = 2 wave-pairs; pair 0 tiles
// [0,hA), pair 1 [hA,qt]; per-pair 16 KB K/V LDS; in-block (o,l) combine.
// S^T = K.Q^T with PERM'd key order; P^T fragments register-local.
// Softmax: exp2-folded + v_cvt_pk_bf16_f32 packing.
// ---------------------------------------------------------------------------
__global__ __launch_bounds__(256) void fire_attn_mfma(
    const ushort_t* __restrict__ Qg, const ushort_t* __restrict__ Kg,
    const ushort_t* __restrict__ Vtg, const ushort_t* __restrict__ biaspre,
    ushort_t* __restrict__ Ob) {
  __shared__ __align__(16) ushort_t sKV[16384];  // K: pair*4096, V: 8192+pair*4096
  const int tid = threadIdx.x;
  const int lane = tid & 63, w = tid >> 6;
  const int pair = w >> 1, wq = w & 1;           // pair 0/1; wave-within-pair
  const int quad = lane >> 4, l16 = lane & 15;
  const int g = blockIdx.x >> 6;
  const int qt = (g < 8) ? (15 - g) : (g - 8);
  const int bh = blockIdx.x & 63, h = bh & 7, b = bh >> 3;
  const int tid2 = wq * 64 + lane;               // 0..127 within pair

  bf16x8 q[2][2];
  {
    const size_t qb = (size_t)bh * S_LEN + qt * 64 + wq * 32;
    #pragma unroll
    for (int qg = 0; qg < 2; ++qg)
      #pragma unroll
      for (int ks = 0; ks < 2; ++ks)
        q[qg][ks] = *(const bf16x8*)&Qg[(qb + qg * 16 + l16) * KDIM + ks * 32 + quad * 8];
  }

  const size_t kb = (size_t)bh * S_LEN * KDIM;
  const ushort_t* bptr = &biaspre[((size_t)(h * 136 + TRI(qt)) * 128 + tid2) * 32];
  const int srow8 = lane >> 3;   // staging row-within-group
  const int sc = lane & 7;       // staging chunk

  ushort_t* Kp = sKV + pair * 4096;
  ushort_t* Vp = sKV + 8192 + pair * 4096;

  auto stageKV = [&](int t) {
    #pragma unroll
    for (int j = 0; j < 4; ++j) {
      const int row = (wq * 4 + j) * 8 + srow8;
      const int cc = sc ^ SWZ(row);
      gl_lds16(&Kg[kb + (size_t)(t * 64 + row) * 64 + cc * 8], &Kp[(wq * 4 + j) * 512]);
      gl_lds16(&Vtg[kb + (size_t)row * 1024 + t * 64 + cc * 8], &Vp[(wq * 4 + j) * 512]);
    }
  };

  f32x4 o[2][4];
  float ll[2] = {0.f, 0.f};
  #pragma unroll
  for (int qg = 0; qg < 2; ++qg)
    #pragma unroll
    for (int nb = 0; nb < 4; ++nb) o[qg][nb] = (f32x4)0.0f;

  const int hA = (qt + 2) >> 1;        // pair 0 tile count (>= pair 1's)
  for (int it = 0; it < hA; ++it) {
    const int t = pair ? (hA + it) : it;
    const bool act = (!pair) || (t <= qt);   // wave-uniform predicate
    if (act) stageKV(t);
    __syncthreads();                   // staging landed (both pairs)
    if (act) {
      uint4 bb0 = ((const uint4*)(bptr + (size_t)t * 4096))[0];
      uint4 bb1 = ((const uint4*)(bptr + (size_t)t * 4096))[1];
      uint4 bb2 = ((const uint4*)(bptr + (size_t)t * 4096))[2];
      uint4 bb3 = ((const uint4*)(bptr + (size_t)t * 4096))[3];

      // ---- S^T = K . Q^T  (keys in PERM order on the m-dim)
      f32x4 s[2][4];
      #pragma unroll
      for (int qg = 0; qg < 2; ++qg)
        #pragma unroll
        for (int nb = 0; nb < 4; ++nb) s[qg][nb] = (f32x4)0.0f;
      #pragma unroll
      for (int ks = 0; ks < 2; ++ks) {
        #pragma unroll
        for (int nb = 0; nb < 4; ++nb) {
          const int rk = PERM(nb * 16 + l16);
          bf16x8 ak = *(const bf16x8*)&Kp[rk * 64 + (((ks * 4 + quad) ^ SWZ(rk)) * 8)];
          #pragma unroll
          for (int qg = 0; qg < 2; ++qg)
            s[qg][nb] = __builtin_amdgcn_mfma_f32_16x16x32_bf16(ak, q[qg][ks], s[qg][nb], 0, 0, 0);
        }
      }

      // ---- P = exp2(S + bias); no-max softmax; l per-lane
      unsigned pk[2][4][2];
      #pragma unroll
      for (int qg = 0; qg < 2; ++qg) {
        #pragma unroll
        for (int nb = 0; nb < 4; ++nb) {
          const int v = qg * 16 + nb * 4;
          const uint4& bq = (v < 8) ? bb0 : (v < 16) ? bb1 : (v < 24) ? bb2 : bb3;
          const ushort_t* bu = (const ushort_t*)&bq;
          float p0 = __builtin_amdgcn_exp2f(s[qg][nb][0] + bf2f(bu[(v + 0) & 7]));
          float p1 = __builtin_amdgcn_exp2f(s[qg][nb][1] + bf2f(bu[(v + 1) & 7]));
          float p2 = __builtin_amdgcn_exp2f(s[qg][nb][2] + bf2f(bu[(v + 2) & 7]));
          float p3 = __builtin_amdgcn_exp2f(s[qg][nb][3] + bf2f(bu[(v + 3) & 7]));
          ll[qg] += (p0 + p1) + (p2 + p3);
          pk[qg][nb][0] = cvtpk_bf16(p0, p1);
          pk[qg][nb][1] = cvtpk_bf16(p2, p3);
        }
      }

      // ---- O^T += V^T . P^T (P^T B-frags register-local thanks to PERM)
      #pragma unroll
      for (int ks = 0; ks < 2; ++ks) {
        bf16x8 pf[2];
        #pragma unroll
        for (int qg = 0; qg < 2; ++qg) {
          union { bf16x8 v; unsigned u[4]; } pkx;
          pkx.u[0] = pk[qg][2 * ks][0];
          pkx.u[1] = pk[qg][2 * ks][1];
          pkx.u[2] = pk[qg][2 * ks + 1][0];
          pkx.u[3] = pk[qg][2 * ks + 1][1];
          pf[qg] = pkx.v;
        }
        #pragma unroll
        for (int nb = 0; nb < 4; ++nb) {
          const int rv = nb * 16 + l16;
          bf16x8 av = *(const bf16x8*)&Vp[rv * 64 + (((ks * 4 + quad) ^ SWZ(rv)) * 8)];
          #pragma unroll
          for (int qg = 0; qg < 2; ++qg)
            o[qg][nb] = __builtin_amdgcn_mfma_f32_16x16x32_bf16(av, pf[qg], o[qg][nb], 0, 0, 0);
        }
      }
    }
    __syncthreads();                   // reads done before buffer reuse
  }

  // ---- pair combine via LDS (34 floats/thread-slot; 2-way bank alias = free)
  float* cb = (float*)sKV;
  if (pair == 1) {
    float* my = cb + tid2 * 34;
    #pragma unroll
    for (int qg = 0; qg < 2; ++qg)
      #pragma unroll
      for (int nb = 0; nb < 4; ++nb)
        #pragma unroll
        for (int r = 0; r < 4; ++r) my[qg * 16 + nb * 4 + r] = o[qg][nb][r];
    my[32] = ll[0]; my[33] = ll[1];
  }
  __syncthreads();
  if (pair == 0) {
    const float* pb = cb + tid2 * 34;
    #pragma unroll
    for (int qg = 0; qg < 2; ++qg)
      #pragma unroll
      for (int nb = 0; nb < 4; ++nb)
        #pragma unroll
        for (int r = 0; r < 4; ++r) o[qg][nb][r] += pb[qg * 16 + nb * 4 + r];
    ll[0] += pb[32]; ll[1] += pb[33];

    #pragma unroll
    for (int qg = 0; qg < 2; ++qg) {
      float rs = ll[qg];
      rs += __shfl_xor(rs, 16);
      rs += __shfl_xor(rs, 32);
      const float rl = 1.0f / rs;
      const size_t ob = ((size_t)(b * S_LEN + qt * 64 + wq * 32 + qg * 16 + l16)) * 512 + h * KDIM;
      #pragma unroll
      for (int nb = 0; nb < 4; ++nb) {
        ushort4 ov;
        ov.x = f2bf(o[qg][nb][0] * rl);
        ov.y = f2bf(o[qg][nb][1] * rl);
        ov.z = f2bf(o[qg][nb][2] * rl);
        ov.w = f2bf(o[qg][nb][3] * rl);
        *(ushort4*)&Ob[ob + nb * 16 + quad * 4] = ov;
      }
    }
  }
}

// ---------------------------------------------------------------------------
extern "C" void kernel_launch(void* const* d_in, const int* in_sizes, int n_in,
                              void* d_out, int out_size, void* d_ws, size_t ws_size,
                              hipStream_t stream) {
  const float* src   = (const float*)d_in[0];
  const float* Wq    = (const float*)d_in[1];
  const float* Wk    = (const float*)d_in[2];
  const float* Wv    = (const float*)d_in[3];
  const float* c_raw = (const float*)d_in[4];
  const float* Lp    = (const float*)d_in[5];
  const float* w1    = (const float*)d_in[6];
  const float* b1    = (const float*)d_in[7];
  const float* W2    = (const float*)d_in[8];
  const float* b2    = (const float*)d_in[9];
  const float* w3    = (const float*)d_in[10];
  const float* b3    = (const float*)d_in[11];
  const float* Wo    = (const float*)d_in[12];
  float* outp = (float*)d_out;

  const size_t SRC_E = 4194304;   // 8*1024*512
  const size_t W_E   = 262144;    // 512*512
  const size_t QKV_E = 4194304;   // 64*1024*64
  ushort_t* srcb = (ushort_t*)d_ws;
  ushort_t* Wqb  = srcb + SRC_E;
  ushort_t* Wkb  = Wqb + W_E;
  ushort_t* Wvb  = Wkb + W_E;
  ushort_t* Wob  = Wvb + W_E;
  ushort_t* Qb   = Wob + W_E;
  ushort_t* Kb   = Qb + QKV_E;
  ushort_t* Vtb  = Kb + QKV_E;    // V transposed: [b,h,kd,s]
  ushort_t* Obb  = Vtb + QKV_E;
  ushort_t* biaspre = Obb + QKV_E;                 // 8*136*128*32 ushorts
  float* numb  = (float*)(biaspre + (size_t)NHEAD * 136 * 128 * 32);
  float* rdenb = numb + NHEAD * S_LEN;
  float* gtabb = rdenb + NHEAD * S_LEN;

  // 1) bf16 convert + FIRE tables (independent, merged)
  hipLaunchKernelGGL(prep, dim3(7176), dim3(256), 0, stream,
                     src, Wq, Wk, Wv, Wo, srcb, Wqb, Wkb, Wvb, Wob,
                     c_raw, Lp, w1, b1, W2, b2, w3, b3, numb, rdenb, gtabb);
  // 2) z-fused QKV GEMM (512 blocks of 128x64) + bias-pre (544 blocks)
  hipLaunchKernelGGL(gemm_bias, dim3(1056), dim3(256), 0, stream,
                     srcb, Wqb, Wkb, Wvb, (void*)Qb, (void*)Kb, (void*)Vtb,
                     1, 512, numb, rdenb, gtabb, biaspre);
  // 3) attention (split-KV: 256 thr, 2 wave-pairs per block)
  hipLaunchKernelGGL(fire_attn_mfma, dim3(1024), dim3(256), 0, stream,
                     Qb, Kb, Vtb, biaspre, Obb);
  // 4) output projection (f32 out, 512 blocks of 128x64)
  hipLaunchKernelGGL(gemm_bias, dim3(512), dim3(256), 0, stream,
                     Obb, Wob, Wob, Wob, (void*)outp, (void*)outp, (void*)outp,
                     0, 512, numb, rdenb, gtabb, biaspre);
}

// Round 10
// 155.226 us; speedup vs baseline: 1.0625x; 1.0625x over previous
//
#include <hip/hip_runtime.h>
#include <math.h>

#define S_LEN 1024
#define NHEAD 8
#define BATCH 8
#define KDIM  64
#define HID   32
#define NT    2048
#define LOG2E 1.4426950408889634f
#define TRI(q) ((q) * ((q) + 1) / 2)
// key-order bit-shuffle: m=[nb1 nb0 q1 q0 r1 r0] -> key=[nb1 q1 q0 nb0 r1 r0]
#define PERM(m) (((m) & 0x20) | (((m) & 0x0C) << 1) | (((m) & 0x10) >> 2) | ((m) & 3))
// LDS column swizzle key per row (3 bits, conflict-free for K(perm) and V reads)
#define SWZ(row) (((((row) >> 3) & 1) << 2) | ((row) & 3))

typedef __attribute__((ext_vector_type(8))) short bf16x8;
typedef __attribute__((ext_vector_type(4))) float f32x4;
typedef unsigned short ushort_t;

__device__ inline ushort_t f2bf(float f) {
  union { float f; unsigned u; } v; v.f = f;
  unsigned u = v.u;
  return (ushort_t)((u + 0x7FFFu + ((u >> 16) & 1u)) >> 16);
}
__device__ inline float bf2f(ushort_t u) {
  union { unsigned x; float f; } v; v.x = ((unsigned)u) << 16; return v.f;
}
__device__ inline unsigned cvtpk_bf16(float lo, float hi) {
  unsigned r;
  asm("v_cvt_pk_bf16_f32 %0, %1, %2" : "=v"(r) : "v"(lo), "v"(hi));
  return r;
}

// async global->LDS 16B: lane's LDS dest = lds_base + lane*16 (wave-uniform base)
__device__ inline void gl_lds16(const ushort_t* g, ushort_t* l) {
  __builtin_amdgcn_global_load_lds(
      (const __attribute__((address_space(1))) unsigned int*)g,
      (__attribute__((address_space(3))) unsigned int*)l, 16, 0, 0);
}

// ---------------------------------------------------------------------------
// Kernel 1: prep = to_bf16 (blocks 0..5119) + fire_tables (blocks 5120..7175).
// Q weights pre-scaled by (1/sqrt(KD)) * log2e and the FIRE bias table by
// log2e so attention softmax uses bare v_exp_f32 (exp2) with no per-value mul.
// ---------------------------------------------------------------------------
__global__ __launch_bounds__(256) void prep(
    const float* __restrict__ s, const float* __restrict__ wq,
    const float* __restrict__ wk, const float* __restrict__ wv,
    const float* __restrict__ wo,
    ushort_t* __restrict__ sb, ushort_t* __restrict__ wqb,
    ushort_t* __restrict__ wkb, ushort_t* __restrict__ wvb,
    ushort_t* __restrict__ wob,
    const float* __restrict__ c_raw, const float* __restrict__ Lp,
    const float* __restrict__ w1, const float* __restrict__ b1,
    const float* __restrict__ W2, const float* __restrict__ b2,
    const float* __restrict__ w3, const float* __restrict__ b3,
    float* __restrict__ num_g, float* __restrict__ rden_g,
    float* __restrict__ gtab_g) {
  __shared__ float h1s[8][33];
  const int bx = blockIdx.x;
  const int tid = threadIdx.x;
  if (bx < 5120) {
    const float* src; ushort_t* dst; int base; float scale = 1.0f;
    if (bx < 4096)      { src = s;  dst = sb;  base = bx; }
    else if (bx < 4352) { src = wq; dst = wqb; base = bx - 4096; scale = 0.125f * LOG2E; }
    else if (bx < 4608) { src = wk; dst = wkb; base = bx - 4352; }
    else if (bx < 4864) { src = wv; dst = wvb; base = bx - 4608; }
    else                { src = wo; dst = wob; base = bx - 4864; }
    const int i = (base * 256 + tid) * 4;
    float4 v = *(const float4*)&src[i];
    ushort4 o;
    o.x = f2bf(v.x * scale); o.y = f2bf(v.y * scale);
    o.z = f2bf(v.z * scale); o.w = f2bf(v.w * scale);
    *(ushort4*)&dst[i] = o;
  } else {
    const int idx = bx - 5120;
    const int h = idx / 257;
    const int xb = idx % 257;
    const float cr = c_raw[h];
    const float c = (cr > 20.f) ? cr : log1pf(expf(cr));
    const int gid = xb * 256 + tid;
    if (gid < S_LEN) {
      num_g[h * S_LEN + gid] = log1pf(c * (float)gid);
      rden_g[h * S_LEN + gid] = 1.0f / log1pf(c * fmaxf(Lp[h], (float)(gid + 1)));
    }
    const int pl = tid >> 5;             // point-local 0..7
    const int j = tid & 31;              // hidden dim
    const int pt = xb * 8 + pl;
    const float x = (float)pt * (1.0f / NT);
    float v = x * w1[h * HID + j] + b1[h * HID + j];
    h1s[pl][j] = 0.5f * v * (1.0f + erff(v * 0.70710678118f));
    __syncthreads();
    float sm = b2[h * HID + j];
    const float* w2r = W2 + ((size_t)(h * HID + j)) * HID;
    #pragma unroll
    for (int k = 0; k < HID; ++k) sm += w2r[k] * h1s[pl][k];
    float g = 0.5f * sm * (1.0f + erff(sm * 0.70710678118f));
    float y = w3[h * HID + j] * g;
    #pragma unroll
    for (int off = 1; off < 32; off <<= 1) y += __shfl_xor(y, off);
    if (j == 0 && pt <= NT) gtab_g[h * (NT + 1) + pt] = (y + b3[h]) * LOG2E;
  }
}

// ---------------------------------------------------------------------------
// Z-FUSED QKV tile (R8 best-measured config, 157.8 us): one block computes
// Q, K, V for its 64x64 (m0,n0) tile from a SINGLE A staging. LDS 32 KB =
// A(8K) + Wq/Wk/Wv(24K), acc[3][4], 24 MFMA per K-step, 1024 blocks =
// 4 blocks/CU (16 waves/CU). R9's BM=128 variant (48 MFMA/step but only
// 2 blocks/CU) regressed +7 us: the barrier-drain chain is hidden by
// CROSS-BLOCK TLP, so density gains must not drop blocks/CU below 4.
// ---------------------------------------------------------------------------
__device__ __forceinline__ void qkv_tile(
    ushort_t* sAB, const ushort_t* __restrict__ A,
    const ushort_t* __restrict__ Wq_, const ushort_t* __restrict__ Wk_,
    const ushort_t* __restrict__ Wv_,
    ushort_t* __restrict__ Qo, ushort_t* __restrict__ Ko,
    ushort_t* __restrict__ Vto, int m0, int n0, int tid) {
  ushort_t* sA = sAB;                  // 64x64 bf16 = 8 KB
  ushort_t* sW = sAB + 4096;           // 3 x 8 KB, z-major
  const int lane = tid & 63, w = tid >> 6, quad = lane >> 4, l16 = lane & 15;
  f32x4 acc[3][4];
  #pragma unroll
  for (int z = 0; z < 3; ++z)
    #pragma unroll
    for (int nb = 0; nb < 4; ++nb) acc[z][nb] = (f32x4)0.0f;

  const int r8 = lane >> 3;          // row within 8-row staging group
  const int gc = (lane & 7) ^ r8;    // swizzled source chunk for this lane
  const int sw = l16 & 7;            // frag-read swizzle key
  const ushort_t* Wz[3] = {Wq_, Wk_, Wv_};

  for (int kt = 0; kt < 512; kt += 64) {
    __syncthreads();
    #pragma unroll
    for (int j = 0; j < 2; ++j) {
      const int row = w * 16 + j * 8 + r8;
      gl_lds16(&A[(size_t)(m0 + row) * 512 + kt + gc * 8], &sA[(w * 16 + j * 8) * 64]);
      #pragma unroll
      for (int z = 0; z < 3; ++z)
        gl_lds16(&Wz[z][(size_t)(n0 + row) * 512 + kt + gc * 8],
                 &sW[z * 4096 + (w * 16 + j * 8) * 64]);
    }
    __syncthreads();
    #pragma unroll
    for (int ks = 0; ks < 2; ++ks) {
      const int off = ((ks * 4 + quad) ^ sw) * 8;
      bf16x8 af = *(const bf16x8*)&sA[(w * 16 + l16) * 64 + off];
      #pragma unroll
      for (int z = 0; z < 3; ++z)
        #pragma unroll
        for (int nb = 0; nb < 4; ++nb) {
          bf16x8 wf = *(const bf16x8*)&sW[z * 4096 + (nb * 16 + l16) * 64 + off];
          acc[z][nb] = __builtin_amdgcn_mfma_f32_16x16x32_bf16(af, wf, acc[z][nb], 0, 0, 0);
        }
    }
  }

  // ---- epilogue. z=0 (Q), z=1 (K): bf16 scatter [b,h,s,kd] (no LDS).
  const int bb = m0 >> 10, sbase = m0 & 1023;
  #pragma unroll
  for (int z = 0; z < 2; ++z) {
    ushort_t* outp = z ? Ko : Qo;
    #pragma unroll
    for (int nb = 0; nb < 4; ++nb)
      #pragma unroll
      for (int r = 0; r < 4; ++r) {
        int m = m0 + w * 16 + quad * 4 + r;
        int n = n0 + nb * 16 + l16;
        int ss = m & 1023, hh = n >> 6, kd = n & 63;
        outp[(((size_t)(bb * NHEAD + hh)) * S_LEN + ss) * KDIM + kd] = f2bf(acc[z][nb][r]);
      }
  }
  // z=2 (V): V^T via LDS transpose (XOR-swizzled [n][m]) -> [b,h,kd,s]
  __syncthreads();
  #pragma unroll
  for (int nb = 0; nb < 4; ++nb)
    #pragma unroll
    for (int r = 0; r < 4; ++r) {
      int nl = nb * 16 + l16;
      int ml = w * 16 + quad * 4 + r;
      sAB[nl * 64 + (((ml >> 3) ^ (nl & 7)) * 8) + (ml & 7)] = f2bf(acc[2][nb][r]);
    }
  __syncthreads();
  const int nl = tid >> 2, seg = tid & 3;
  const int ng = n0 + nl, hh = ng >> 6, kd = ng & 63;
  ushort_t* vout = Vto + (((size_t)(bb * NHEAD + hh)) * KDIM + kd) * S_LEN;
  #pragma unroll
  for (int c2 = 0; c2 < 2; ++c2) {
    int mc = seg * 2 + c2;
    bf16x8 vr = *(bf16x8*)&sAB[nl * 64 + ((mc ^ (nl & 7)) * 8)];
    *(bf16x8*)&vout[sbase + mc * 8] = vr;
  }
}

// ---------------------------------------------------------------------------
// Plain GEMM tile (out-proj): C = A(Mx512 bf16) * W^T, 64x64 tile, 4 waves,
// BK=64, single-buffer global_load_lds staging. f32 out.
// ---------------------------------------------------------------------------
__device__ __forceinline__ void gemm_tile(
    ushort_t* sAB, const ushort_t* __restrict__ A, const ushort_t* __restrict__ Wp,
    float* __restrict__ outp, int m0, int n0, int tid) {
  ushort_t* sA = sAB;            // 64x64
  ushort_t* sB = sAB + 4096;
  const int lane = tid & 63, w = tid >> 6, quad = lane >> 4, l16 = lane & 15;
  f32x4 acc[4];
  #pragma unroll
  for (int nb = 0; nb < 4; ++nb) acc[nb] = (f32x4)0.0f;

  const int r8 = lane >> 3;
  const int gc = (lane & 7) ^ r8;
  const int sw = l16 & 7;

  for (int kt = 0; kt < 512; kt += 64) {
    __syncthreads();
    #pragma unroll
    for (int j = 0; j < 2; ++j) {
      const int row = w * 16 + j * 8 + r8;
      gl_lds16(&A[(size_t)(m0 + row) * 512 + kt + gc * 8], &sA[(w * 16 + j * 8) * 64]);
      gl_lds16(&Wp[(size_t)(n0 + row) * 512 + kt + gc * 8], &sB[(w * 16 + j * 8) * 64]);
    }
    __syncthreads();
    #pragma unroll
    for (int ks = 0; ks < 2; ++ks) {
      const int off = ((ks * 4 + quad) ^ sw) * 8;
      bf16x8 af = *(bf16x8*)&sA[(w * 16 + l16) * 64 + off];
      #pragma unroll
      for (int nb = 0; nb < 4; ++nb) {
        bf16x8 bfr = *(bf16x8*)&sB[(nb * 16 + l16) * 64 + off];
        acc[nb] = __builtin_amdgcn_mfma_f32_16x16x32_bf16(af, bfr, acc[nb], 0, 0, 0);
      }
    }
  }
  #pragma unroll
  for (int nb = 0; nb < 4; ++nb) {
    #pragma unroll
    for (int r = 0; r < 4; ++r) {
      int m = m0 + w * 16 + quad * 4 + r;
      int n = n0 + nb * 16 + l16;
      outp[(size_t)m * 512 + n] = acc[nb][r];
    }
  }
}

// ---------------------------------------------------------------------------
// Kernel 2/4: gemm_bias. scatter=1: blocks < nGemm are z-fused QKV tiles
// (1024 blocks, m0=(tile&127)*64, n0=(tile>>7)*64); blocks >= nGemm are
// bias-pre. scatter=0: out-proj (f32 out).
// ---------------------------------------------------------------------------
__global__ __launch_bounds__(256) void gemm_bias(
    const ushort_t* __restrict__ A,
    const ushort_t* __restrict__ W0, const ushort_t* __restrict__ W1,
    const ushort_t* __restrict__ W2w,
    void* __restrict__ out0, void* __restrict__ out1, void* __restrict__ out2,
    int scatter, int nGemm,
    const float* __restrict__ num_g, const float* __restrict__ rden_g,
    const float* __restrict__ gtab_g, ushort_t* __restrict__ biaspre) {
  __shared__ __align__(16) ushort_t sAB[16384];   // 32 KB
  const int tid = threadIdx.x;
  if ((int)blockIdx.x < nGemm) {
    const int tile = blockIdx.x;
    const int m0 = (tile & 127) * 64;
    const int n0 = (tile >> 7) * 64;
    if (scatter) {
      qkv_tile(sAB, A, W0, W1, W2w, (ushort_t*)out0, (ushort_t*)out1,
               (ushort_t*)out2, m0, n0, tid);
    } else {
      gemm_tile(sAB, A, W0, (float*)out0, m0, n0, tid);
    }
  } else {
    const int idx = blockIdx.x - nGemm;      // 0..543
    const int h = idx / 68;
    const int pair = idx % 68;
    float* gtab_s = (float*)sAB;             // 2049 floats
    float* num_s = gtab_s + 2052;            // 1024 floats
    float* rden_s = num_s + 1024;            // [2][64]  (total ~12.9 KB < 32 KB)
    for (int i = tid; i <= NT; i += 256) gtab_s[i] = gtab_g[h * (NT + 1) + i];
    for (int i = tid; i < S_LEN; i += 256) num_s[i] = num_g[h * S_LEN + i];
    const int sub = tid >> 7, tid2 = tid & 127;
    const int tileIdx = pair * 2 + sub;
    int qt = 0;
    while (TRI(qt + 1) <= tileIdx) ++qt;
    const int t = tileIdx - TRI(qt);
    if (tid2 < 64) rden_s[sub * 64 + tid2] = rden_g[h * S_LEN + qt * 64 + tid2];
    __syncthreads();
    const int w = tid2 >> 6, lane = tid2 & 63, quad = lane >> 4, l16 = lane & 15;
    ushort_t vals[32];
    #pragma unroll
    for (int qg = 0; qg < 2; ++qg) {
      const int iloc = w * 32 + qg * 16 + l16;
      const int i = qt * 64 + iloc;
      const float rden = rden_s[sub * 64 + iloc];
      #pragma unroll
      for (int nb = 0; nb < 4; ++nb)
        #pragma unroll
        for (int r = 0; r < 4; ++r) {
          const int m = nb * 16 + quad * 4 + r;
          const int j = t * 64 + PERM(m);
          ushort_t out;
          if (j > i) {
            out = 0xFF80;  // bf16 -inf (causal)
          } else {
            const int d = i - j;
            float x = num_s[d] * rden;       // in [0,1)
            float tf = x * (float)NT;
            int it = (int)tf; it = it < (NT - 1) ? it : (NT - 1);
            float fr = tf - (float)it;
            float ga = gtab_s[it];
            out = f2bf(ga + (gtab_s[it + 1] - ga) * fr);
          }
          vals[qg * 16 + nb * 4 + r] = out;
        }
    }
    ushort_t* dst = &biaspre[((size_t)(h * 136 + tileIdx) * 128 + tid2) * 32];
    uint4 u[2];
    #pragma unroll
    for (int half = 0; half < 2; ++half) {
      #pragma unroll
      for (int v = 0; v < 8; ++v) ((ushort_t*)&u[0])[v] = vals[half * 16 + v];
      #pragma unroll
      for (int v = 0; v < 8; ++v) ((ushort_t*)&u[1])[v] = vals[half * 16 + 8 + v];
      *(uint4*)(dst + half * 16) = u[0];
      *(uint4*)(dst + half * 16 + 8) = u[1];
    }
  }
}

// ---------------------------------------------------------------------------
// Kernel 3: transposed MFMA causal flash attention, SPLIT-KV (R7 config,
// measured -7 us). 1024 blocks x 256 thr = 2 wave-pairs; pair 0 tiles
// [0,hA), pair 1 [hA,qt]; per-pair 16 KB K/V LDS; in-block (o,l) combine.
// S^T = K.Q^T with PERM'd key order; P^T fragments register-local.
// Softmax: exp2-folded + v_cvt_pk_bf16_f32 packing.
// ---------------------------------------------------------------------------
__global__ __launch_bounds__(256) void fire_attn_mfma(
    const ushort_t* __restrict__ Qg, const ushort_t* __restrict__ Kg,
    const ushort_t* __restrict__ Vtg, const ushort_t* __restrict__ biaspre,
    ushort_t* __restrict__ Ob) {
  __shared__ __align__(16) ushort_t sKV[16384];  // K: pair*4096, V: 8192+pair*4096
  const int tid = threadIdx.x;
  const int lane = tid & 63, w = tid >> 6;
  const int pair = w >> 1, wq = w & 1;           // pair 0/1; wave-within-pair
  const int quad = lane >> 4, l16 = lane & 15;
  const int g = blockIdx.x >> 6;
  const int qt = (g < 8) ? (15 - g) : (g - 8);
  const int bh = blockIdx.x & 63, h = bh & 7, b = bh >> 3;
  const int tid2 = wq * 64 + lane;               // 0..127 within pair

  bf16x8 q[2][2];
  {
    const size_t qb = (size_t)bh * S_LEN + qt * 64 + wq * 32;
    #pragma unroll
    for (int qg = 0; qg < 2; ++qg)
      #pragma unroll
      for (int ks = 0; ks < 2; ++ks)
        q[qg][ks] = *(const bf16x8*)&Qg[(qb + qg * 16 + l16) * KDIM + ks * 32 + quad * 8];
  }

  const size_t kb = (size_t)bh * S_LEN * KDIM;
  const ushort_t* bptr = &biaspre[((size_t)(h * 136 + TRI(qt)) * 128 + tid2) * 32];
  const int srow8 = lane >> 3;   // staging row-within-group
  const int sc = lane & 7;       // staging chunk

  ushort_t* Kp = sKV + pair * 4096;
  ushort_t* Vp = sKV + 8192 + pair * 4096;

  auto stageKV = [&](int t) {
    #pragma unroll
    for (int j = 0; j < 4; ++j) {
      const int row = (wq * 4 + j) * 8 + srow8;
      const int cc = sc ^ SWZ(row);
      gl_lds16(&Kg[kb + (size_t)(t * 64 + row) * 64 + cc * 8], &Kp[(wq * 4 + j) * 512]);
      gl_lds16(&Vtg[kb + (size_t)row * 1024 + t * 64 + cc * 8], &Vp[(wq * 4 + j) * 512]);
    }
  };

  f32x4 o[2][4];
  float ll[2] = {0.f, 0.f};
  #pragma unroll
  for (int qg = 0; qg < 2; ++qg)
    #pragma unroll
    for (int nb = 0; nb < 4; ++nb) o[qg][nb] = (f32x4)0.0f;

  const int hA = (qt + 2) >> 1;        // pair 0 tile count (>= pair 1's)
  for (int it = 0; it < hA; ++it) {
    const int t = pair ? (hA + it) : it;
    const bool act = (!pair) || (t <= qt);   // wave-uniform predicate
    if (act) stageKV(t);
    __syncthreads();                   // staging landed (both pairs)
    if (act) {
      uint4 bb0 = ((const uint4*)(bptr + (size_t)t * 4096))[0];
      uint4 bb1 = ((const uint4*)(bptr + (size_t)t * 4096))[1];
      uint4 bb2 = ((const uint4*)(bptr + (size_t)t * 4096))[2];
      uint4 bb3 = ((const uint4*)(bptr + (size_t)t * 4096))[3];

      // ---- S^T = K . Q^T  (keys in PERM order on the m-dim)
      f32x4 s[2][4];
      #pragma unroll
      for (int qg = 0; qg < 2; ++qg)
        #pragma unroll
        for (int nb = 0; nb < 4; ++nb) s[qg][nb] = (f32x4)0.0f;
      #pragma unroll
      for (int ks = 0; ks < 2; ++ks) {
        #pragma unroll
        for (int nb = 0; nb < 4; ++nb) {
          const int rk = PERM(nb * 16 + l16);
          bf16x8 ak = *(const bf16x8*)&Kp[rk * 64 + (((ks * 4 + quad) ^ SWZ(rk)) * 8)];
          #pragma unroll
          for (int qg = 0; qg < 2; ++qg)
            s[qg][nb] = __builtin_amdgcn_mfma_f32_16x16x32_bf16(ak, q[qg][ks], s[qg][nb], 0, 0, 0);
        }
      }

      // ---- P = exp2(S + bias); no-max softmax; l per-lane
      unsigned pk[2][4][2];
      #pragma unroll
      for (int qg = 0; qg < 2; ++qg) {
        #pragma unroll
        for (int nb = 0; nb < 4; ++nb) {
          const int v = qg * 16 + nb * 4;
          const uint4& bq = (v < 8) ? bb0 : (v < 16) ? bb1 : (v < 24) ? bb2 : bb3;
          const ushort_t* bu = (const ushort_t*)&bq;
          float p0 = __builtin_amdgcn_exp2f(s[qg][nb][0] + bf2f(bu[(v + 0) & 7]));
          float p1 = __builtin_amdgcn_exp2f(s[qg][nb][1] + bf2f(bu[(v + 1) & 7]));
          float p2 = __builtin_amdgcn_exp2f(s[qg][nb][2] + bf2f(bu[(v + 2) & 7]));
          float p3 = __builtin_amdgcn_exp2f(s[qg][nb][3] + bf2f(bu[(v + 3) & 7]));
          ll[qg] += (p0 + p1) + (p2 + p3);
          pk[qg][nb][0] = cvtpk_bf16(p0, p1);
          pk[qg][nb][1] = cvtpk_bf16(p2, p3);
        }
      }

      // ---- O^T += V^T . P^T (P^T B-frags register-local thanks to PERM)
      #pragma unroll
      for (int ks = 0; ks < 2; ++ks) {
        bf16x8 pf[2];
        #pragma unroll
        for (int qg = 0; qg < 2; ++qg) {
          union { bf16x8 v; unsigned u[4]; } pkx;
          pkx.u[0] = pk[qg][2 * ks][0];
          pkx.u[1] = pk[qg][2 * ks][1];
          pkx.u[2] = pk[qg][2 * ks + 1][0];
          pkx.u[3] = pk[qg][2 * ks + 1][1];
          pf[qg] = pkx.v;
        }
        #pragma unroll
        for (int nb = 0; nb < 4; ++nb) {
          const int rv = nb * 16 + l16;
          bf16x8 av = *(const bf16x8*)&Vp[rv * 64 + (((ks * 4 + quad) ^ SWZ(rv)) * 8)];
          #pragma unroll
          for (int qg = 0; qg < 2; ++qg)
            o[qg][nb] = __builtin_amdgcn_mfma_f32_16x16x32_bf16(av, pf[qg], o[qg][nb], 0, 0, 0);
        }
      }
    }
    __syncthreads();                   // reads done before buffer reuse
  }

  // ---- pair combine via LDS (34 floats/thread-slot; 2-way bank alias = free)
  float* cb = (float*)sKV;
  if (pair == 1) {
    float* my = cb + tid2 * 34;
    #pragma unroll
    for (int qg = 0; qg < 2; ++qg)
      #pragma unroll
      for (int nb = 0; nb < 4; ++nb)
        #pragma unroll
        for (int r = 0; r < 4; ++r) my[qg * 16 + nb * 4 + r] = o[qg][nb][r];
    my[32] = ll[0]; my[33] = ll[1];
  }
  __syncthreads();
  if (pair == 0) {
    const float* pb = cb + tid2 * 34;
    #pragma unroll
    for (int qg = 0; qg < 2; ++qg)
      #pragma unroll
      for (int nb = 0; nb < 4; ++nb)
        #pragma unroll
        for (int r = 0; r < 4; ++r) o[qg][nb][r] += pb[qg * 16 + nb * 4 + r];
    ll[0] += pb[32]; ll[1] += pb[33];

    #pragma unroll
    for (int qg = 0; qg < 2; ++qg) {
      float rs = ll[qg];
      rs += __shfl_xor(rs, 16);
      rs += __shfl_xor(rs, 32);
      const float rl = 1.0f / rs;
      const size_t ob = ((size_t)(b * S_LEN + qt * 64 + wq * 32 + qg * 16 + l16)) * 512 + h * KDIM;
      #pragma unroll
      for (int nb = 0; nb < 4; ++nb) {
        ushort4 ov;
        ov.x = f2bf(o[qg][nb][0] * rl);
        ov.y = f2bf(o[qg][nb][1] * rl);
        ov.z = f2bf(o[qg][nb][2] * rl);
        ov.w = f2bf(o[qg][nb][3] * rl);
        *(ushort4*)&Ob[ob + nb * 16 + quad * 4] = ov;
      }
    }
  }
}

// ---------------------------------------------------------------------------
extern "C" void kernel_launch(void* const* d_in, const int* in_sizes, int n_in,
                              void* d_out, int out_size, void* d_ws, size_t ws_size,
                              hipStream_t stream) {
  const float* src   = (const float*)d_in[0];
  const float* Wq    = (const float*)d_in[1];
  const float* Wk    = (const float*)d_in[2];
  const float* Wv    = (const float*)d_in[3];
  const float* c_raw = (const float*)d_in[4];
  const float* Lp    = (const float*)d_in[5];
  const float* w1    = (const float*)d_in[6];
  const float* b1    = (const float*)d_in[7];
  const float* W2    = (const float*)d_in[8];
  const float* b2    = (const float*)d_in[9];
  const float* w3    = (const float*)d_in[10];
  const float* b3    = (const float*)d_in[11];
  const float* Wo    = (const float*)d_in[12];
  float* outp = (float*)d_out;

  const size_t SRC_E = 4194304;   // 8*1024*512
  const size_t W_E   = 262144;    // 512*512
  const size_t QKV_E = 4194304;   // 64*1024*64
  ushort_t* srcb = (ushort_t*)d_ws;
  ushort_t* Wqb  = srcb + SRC_E;
  ushort_t* Wkb  = Wqb + W_E;
  ushort_t* Wvb  = Wkb + W_E;
  ushort_t* Wob  = Wvb + W_E;
  ushort_t* Qb   = Wob + W_E;
  ushort_t* Kb   = Qb + QKV_E;
  ushort_t* Vtb  = Kb + QKV_E;    // V transposed: [b,h,kd,s]
  ushort_t* Obb  = Vtb + QKV_E;
  ushort_t* biaspre = Obb + QKV_E;                 // 8*136*128*32 ushorts
  float* numb  = (float*)(biaspre + (size_t)NHEAD * 136 * 128 * 32);
  float* rdenb = numb + NHEAD * S_LEN;
  float* gtabb = rdenb + NHEAD * S_LEN;

  // 1) bf16 convert + FIRE tables (independent, merged)
  hipLaunchKernelGGL(prep, dim3(7176), dim3(256), 0, stream,
                     src, Wq, Wk, Wv, Wo, srcb, Wqb, Wkb, Wvb, Wob,
                     c_raw, Lp, w1, b1, W2, b2, w3, b3, numb, rdenb, gtabb);
  // 2) z-fused QKV GEMM (1024 blocks) + bias-pre (544 blocks)
  hipLaunchKernelGGL(gemm_bias, dim3(1568), dim3(256), 0, stream,
                     srcb, Wqb, Wkb, Wvb, (void*)Qb, (void*)Kb, (void*)Vtb,
                     1, 1024, numb, rdenb, gtabb, biaspre);
  // 3) attention (split-KV: 256 thr, 2 wave-pairs per block)
  hipLaunchKernelGGL(fire_attn_mfma, dim3(1024), dim3(256), 0, stream,
                     Qb, Kb, Vtb, biaspre, Obb);
  // 4) output projection (f32 out, 1024 blocks of 64x64)
  hipLaunchKernelGGL(gemm_bias, dim3(1024), dim3(256), 0, stream,
                     Obb, Wob, Wob, Wob, (void*)outp, (void*)outp, (void*)outp,
                     0, 1024, numb, rdenb, gtabb, biaspre);
}